// Round 5
// baseline (5352.028 us; speedup 1.0000x reference)
//
#include <hip/hip_runtime.h>
#include <math.h>

#define MR_C     256
#define MR_L     8192
#define MR_DEPTH 12
#define TPB      256
#define GPT      8             // contiguous float4 groups per thread
#define NG       (MR_L / 4)    // 2048 groups per row

// R6 THEORY (resubmit after infra failure): four rounds prove the 64-VGPR pin
// is tied to TPB=1024 workgroups (attributes + LDS size don't move it) and
// that all runtime = spill traffic. m97 precedent: TPB=256 kernels get 164
// VGPRs with zero spills. Restructure: 256 threads x 8 contiguous groups,
// res[8]+acc[8] in registers, transposed LDS layout slot(g) = ((g&7)<<8)|(g>>3)
// so every main-loop LDS access is conflict-free (consecutive slots across
// lanes) and every address folds to tid + compile-time constant.

__device__ __forceinline__ float4 f4z() { return make_float4(0.f, 0.f, 0.f, 0.f); }

// Tap fetch for own-run-relative group index E (E = K - delta, constexpr).
// E >= 0: value still in registers (descending-K processing keeps them "old").
// E <  0: neighbor thread's group, read from LDS at tid + folded constant.
template<int E>
__device__ __forceinline__ float4 tap_get(const float4* res, const float4* __restrict__ bc, int tid)
{
    if constexpr (E >= 0) {
        return res[E];
    } else {
        constexpr int em = ((E % 8) + 8) % 8;   // true mod 8
        constexpr int ef = (E - em) / 8;        // floor div 8 (negative)
        return (tid + ef >= 0) ? bc[(em << 8) + tid + ef] : f4z();
    }
}

template<int LEV, int K>
__device__ __forceinline__ void group_step(
    float4* res, float4* acc, const float4* __restrict__ bc, float4* __restrict__ bn,
    int tid, const float4 F0, const float4 G1)
{
    constexpr int d = 1 << LEV;
    const float4 rl = res[K];
    float4 t1, t2, t3;   // taps at t-d, t-2d, t-3d

    if constexpr (d == 1) {
        const float4 p = tap_get<K - 1>(res, bc, tid);
        t1 = make_float4(p.w, rl.x, rl.y, rl.z);
        t2 = make_float4(p.z, p.w, rl.x, rl.y);
        t3 = make_float4(p.y, p.z, p.w, rl.x);
    } else if constexpr (d == 2) {
        const float4 p  = tap_get<K - 1>(res, bc, tid);
        const float4 p2 = tap_get<K - 2>(res, bc, tid);
        t1 = make_float4(p.z, p.w, rl.x, rl.y);
        t2 = p;
        t3 = make_float4(p2.z, p2.w, p.x, p.y);
    } else {
        constexpr int d4 = d >> 2;              // dilation in whole groups
        t1 = tap_get<K -     d4>(res, bc, tid);
        t2 = tap_get<K - 2 * d4>(res, bc, tid);
        t3 = tap_get<K - 3 * d4>(res, bc, tid);
    }

    // coefficient of x[t - d*j] is h[3-j]; wi pre-folded into G1 = wi*F1
    acc[K].x += G1.w * rl.x + G1.z * t1.x + G1.y * t2.x + G1.x * t3.x;
    acc[K].y += G1.w * rl.y + G1.z * t1.y + G1.y * t2.y + G1.x * t3.y;
    acc[K].z += G1.w * rl.z + G1.z * t1.z + G1.y * t2.z + G1.x * t3.z;
    acc[K].w += G1.w * rl.w + G1.z * t1.w + G1.y * t2.w + G1.x * t3.w;

    float4 nl;
    nl.x = F0.w * rl.x + F0.z * t1.x + F0.y * t2.x + F0.x * t3.x;
    nl.y = F0.w * rl.y + F0.z * t1.y + F0.y * t2.y + F0.x * t3.y;
    nl.z = F0.w * rl.z + F0.z * t1.z + F0.y * t2.z + F0.x * t3.z;
    nl.w = F0.w * rl.w + F0.z * t1.w + F0.y * t2.w + F0.x * t3.w;

    res[K] = nl;
    if constexpr (LEV != MR_DEPTH - 1)
        bn[(K << 8) + tid] = nl;   // consecutive slots across lanes: conflict-free
}

template<int LEV>
__device__ __forceinline__ void do_level(
    float4* res, float4* acc, const float4* __restrict__ bc, float4* __restrict__ bn,
    int tid, const float4 F0, const float4 G1)
{
    // Descending K keeps res[<K] holding OLD (current-level-input) values.
    group_step<LEV, 7>(res, acc, bc, bn, tid, F0, G1);
    group_step<LEV, 6>(res, acc, bc, bn, tid, F0, G1);
    group_step<LEV, 5>(res, acc, bc, bn, tid, F0, G1);
    group_step<LEV, 4>(res, acc, bc, bn, tid, F0, G1);
    group_step<LEV, 3>(res, acc, bc, bn, tid, F0, G1);
    group_step<LEV, 2>(res, acc, bc, bn, tid, F0, G1);
    group_step<LEV, 1>(res, acc, bc, bn, tid, F0, G1);
    group_step<LEV, 0>(res, acc, bc, bn, tid, F0, G1);
}

__global__ __launch_bounds__(TPB) __attribute__((amdgpu_waves_per_eu(2)))
void multires_fused(
    const float* __restrict__ x,
    const float* __restrict__ h0,
    const float* __restrict__ h1,
    const float* __restrict__ w,
    float* __restrict__ out)
{
    __shared__ float4 bufA[NG];
    __shared__ float4 bufB[NG];   // 64 KiB total -> 2 blocks/CU

    const int row = blockIdx.x;            // b*C + c
    const int c   = row & (MR_C - 1);
    const int tid = threadIdx.x;

    // block-uniform filter/weight loads -> SGPRs
    const float4 F0 = ((const float4*)h0)[c];
    const float4 F1 = ((const float4*)h1)[c];
    const float* __restrict__ wrow = w + c * (MR_DEPTH + 2);
    const float wlast = wrow[MR_DEPTH + 1];

    const float4* __restrict__ xrow = (const float4*)(x + (size_t)row * MR_L);

    // slot base for the strided (coalesced-global) <-> transposed-LDS bounce
    const int sbase = ((tid & 7) << 8) + (tid >> 3);

    // prologue: coalesced global loads, scatter into transposed LDS layout
    float4 stage[GPT];
#pragma unroll
    for (int k = 0; k < GPT; ++k) stage[k] = xrow[tid + (k << 8)];
#pragma unroll
    for (int k = 0; k < GPT; ++k) bufA[sbase + k * 32] = stage[k];
    __syncthreads();

    // own contiguous run -> registers; init acc
    float4 res[GPT], acc[GPT];
#pragma unroll
    for (int k = 0; k < GPT; ++k) {
        res[k] = bufA[(k << 8) + tid];     // conflict-free
        acc[k].x = wlast * res[k].x;
        acc[k].y = wlast * res[k].y;
        acc[k].z = wlast * res[k].z;
        acc[k].w = wlast * res[k].w;
    }

    const float4* bc = bufA;
    float4*       bn = bufB;

    // One barrier per level is safe with 2 buffers: writes at level l target the
    // buffer last READ at level l-1, and the sync at end of l-1 separates them.
#define DO_LEVEL(LEV)                                                           \
    {                                                                           \
        const float wi = wrow[MR_DEPTH - (LEV)];                                \
        const float4 G1 = make_float4(wi * F1.x, wi * F1.y, wi * F1.z, wi * F1.w); \
        do_level<LEV>(res, acc, bc, bn, tid, F0, G1);                           \
        if ((LEV) != MR_DEPTH - 1) __syncthreads();                             \
        float4* t_ = bn; bn = (float4*)bc; bc = t_;                             \
    }

    DO_LEVEL(0)  DO_LEVEL(1)  DO_LEVEL(2)  DO_LEVEL(3)
    DO_LEVEL(4)  DO_LEVEL(5)  DO_LEVEL(6)  DO_LEVEL(7)
    DO_LEVEL(8)  DO_LEVEL(9)  DO_LEVEL(10) DO_LEVEL(11)
#undef DO_LEVEL

    // After L11 + final swap, bc = the L9-output buffer, untouched since the
    // barrier after L10 (L11 does no LDS writes) -> safe to reuse, no race.
    float4* ebuf = (float4*)bc;
    const float w0 = wrow[0];
    const float inv_sqrt2 = 0.70710678118654752f;

#pragma unroll
    for (int k = 0; k < GPT; ++k) {
        float4 v; float u;
        u = acc[k].x + w0 * res[k].x; v.x = 0.5f * u * (1.0f + erff(u * inv_sqrt2));
        u = acc[k].y + w0 * res[k].y; v.y = 0.5f * u * (1.0f + erff(u * inv_sqrt2));
        u = acc[k].z + w0 * res[k].z; v.z = 0.5f * u * (1.0f + erff(u * inv_sqrt2));
        u = acc[k].w + w0 * res[k].w; v.w = 0.5f * u * (1.0f + erff(u * inv_sqrt2));
        ebuf[(k << 8) + tid] = v;          // conflict-free
    }
    __syncthreads();

    // coalesced float4 stores via the transposed->strided bounce
    float4* __restrict__ orow = (float4*)(out + (size_t)row * MR_L);
#pragma unroll
    for (int k = 0; k < GPT; ++k)
        orow[tid + (k << 8)] = ebuf[sbase + k * 32];
}

extern "C" void kernel_launch(void* const* d_in, const int* in_sizes, int n_in,
                              void* d_out, int out_size, void* d_ws, size_t ws_size,
                              hipStream_t stream) {
    const float* x  = (const float*)d_in[0];
    const float* h0 = (const float*)d_in[1];
    const float* h1 = (const float*)d_in[2];
    const float* w  = (const float*)d_in[3];
    float* o        = (float*)d_out;

    const int rows = in_sizes[0] / MR_L;   // B*C = 4096
    multires_fused<<<rows, TPB, 0, stream>>>(x, h0, h1, w, o);
}

// Round 6
// 3948.626 us; speedup vs baseline: 1.3554x; 1.3554x over previous
//
#include <hip/hip_runtime.h>
#include <math.h>

#define MR_C     256
#define MR_L     8192
#define MR_DEPTH 12
#define TPB      256
#define NG       (MR_L / 4)    // 2048 float4 groups per row

// R7 THEORY: six rounds show BOTH failure modes punish persistent per-thread
// state: (a) TPB=1024 -> 64-VGPR cap -> allocator spills long-lived regs
// (9-14 GB scratch traffic = 100% of runtime); (b) TPB=256 with float4
// arrays -> SROA failure -> arrays in scratch (localMem) despite 128 free
// VGPRs (14.5 GB). Fix: NO local arrays at all, NO register-resident res.
// State = 8 NAMED float4 accumulators (32 VGPRs) passed individually by
// reference; res/taps are ALWAYS read from LDS (the R1-minimum-traffic
// lesson). Persistent ~45 regs; worst-case hoist fits the 256 cap -> no
// spill possible. Transposed LDS layout slot(g) = ((g&7)<<8)|(g>>3):
// main-loop accesses are conflict-free and fold to tid + compile-time const.

__device__ __forceinline__ float4 f4z() { return make_float4(0.f, 0.f, 0.f, 0.f); }

// Read the tap at own-run-relative group index E (own group K, tap K-D).
// Own groups of thread t are g = t*8+k at LDS slot (k<<8)+t.
template<int E>
__device__ __forceinline__ float4 lds_tap(const float4* __restrict__ bc, const int tid)
{
    if constexpr (E >= 0) {
        return bc[(E << 8) + tid];
    } else {
        constexpr int em = ((E % 8) + 8) % 8;   // true mod 8
        constexpr int ef = (E - em) / 8;        // floor div 8 (negative)
        return (tid + ef >= 0) ? bc[(em << 8) + tid + ef] : f4z();   // causal zero-pad
    }
}

// One group-step. acc is ONE named float4 passed by reference (SROA-trivial).
// coefficient of x[t-d*j] is h[3-j]:  F.w*x[t] + F.z*x[t-d] + F.y*x[t-2d] + F.x*x[t-3d]
// G1 = wi*F1 pre-folded (and for LEV==11, G1 = w1*F1 + w0*F0: the final
// res_lo contribution merges into the last level -> no nl, no LDS write).
template<int LEV, int K>
__device__ __forceinline__ void gstep(
    float4& acc, const float4* __restrict__ bc, float4* __restrict__ bn,
    const int tid, const float4 F0, const float4 G1)
{
    constexpr int d = 1 << LEV;
    const float4 rl = bc[(K << 8) + tid];
    float4 t1, t2, t3;   // taps at t-d, t-2d, t-3d

    if constexpr (d == 1) {
        const float4 p = lds_tap<K - 1>(bc, tid);
        t1 = make_float4(p.w, rl.x, rl.y, rl.z);
        t2 = make_float4(p.z, p.w, rl.x, rl.y);
        t3 = make_float4(p.y, p.z, p.w, rl.x);
    } else if constexpr (d == 2) {
        const float4 p  = lds_tap<K - 1>(bc, tid);
        const float4 p2 = lds_tap<K - 2>(bc, tid);
        t1 = make_float4(p.z, p.w, rl.x, rl.y);
        t2 = p;
        t3 = make_float4(p2.z, p2.w, p.x, p.y);
    } else {
        constexpr int D4 = d >> 2;              // dilation in whole groups
        t1 = lds_tap<K -     D4>(bc, tid);
        t2 = lds_tap<K - 2 * D4>(bc, tid);
        t3 = lds_tap<K - 3 * D4>(bc, tid);
    }

    acc.x += G1.w * rl.x + G1.z * t1.x + G1.y * t2.x + G1.x * t3.x;
    acc.y += G1.w * rl.y + G1.z * t1.y + G1.y * t2.y + G1.x * t3.y;
    acc.z += G1.w * rl.z + G1.z * t1.z + G1.y * t2.z + G1.x * t3.z;
    acc.w += G1.w * rl.w + G1.z * t1.w + G1.y * t2.w + G1.x * t3.w;

    if constexpr (LEV != MR_DEPTH - 1) {
        float4 nl;
        nl.x = F0.w * rl.x + F0.z * t1.x + F0.y * t2.x + F0.x * t3.x;
        nl.y = F0.w * rl.y + F0.z * t1.y + F0.y * t2.y + F0.x * t3.y;
        nl.z = F0.w * rl.z + F0.z * t1.z + F0.y * t2.z + F0.x * t3.z;
        nl.w = F0.w * rl.w + F0.z * t1.w + F0.y * t2.w + F0.x * t3.w;
        bn[(K << 8) + tid] = nl;   // consecutive slots across lanes: conflict-free
    }
}

__global__ __launch_bounds__(TPB) void multires_fused(
    const float* __restrict__ x,
    const float* __restrict__ h0,
    const float* __restrict__ h1,
    const float* __restrict__ w,
    float* __restrict__ out)
{
    __shared__ float4 bufA[NG];
    __shared__ float4 bufB[NG];   // 64 KiB total -> 2 blocks/CU

    const int row = blockIdx.x;            // b*C + c
    const int c   = row & (MR_C - 1);
    const int tid = threadIdx.x;

    // block-uniform filter/weight loads -> scalar regs
    const float4 F0 = ((const float4*)h0)[c];
    const float4 F1 = ((const float4*)h1)[c];
    const float* __restrict__ wrow = w + c * (MR_DEPTH + 2);
    const float wlast = wrow[MR_DEPTH + 1];
    const float w0    = wrow[0];

    const float4* __restrict__ xrow = (const float4*)(x + (size_t)row * MR_L);

    // slot base for the strided (coalesced-global) <-> transposed-LDS bounce
    const int sbase = ((tid & 7) << 8) + (tid >> 3);

    // prologue: coalesced global loads, scatter into transposed LDS layout
#pragma unroll
    for (int k = 0; k < 8; ++k)
        bufA[sbase + k * 32] = xrow[tid + (k << 8)];
    __syncthreads();

    // init 8 NAMED accumulators: a_k = wlast * x(own group k)   (conflict-free reads)
    float4 a0, a1, a2, a3, a4, a5, a6, a7;
#define ACC_INIT(K, A) { const float4 t = bufA[((K) << 8) + tid];               \
        A = make_float4(wlast * t.x, wlast * t.y, wlast * t.z, wlast * t.w); }
    ACC_INIT(0, a0) ACC_INIT(1, a1) ACC_INIT(2, a2) ACC_INIT(3, a3)
    ACC_INIT(4, a4) ACC_INIT(5, a5) ACC_INIT(6, a6) ACC_INIT(7, a7)
#undef ACC_INIT

    const float4* bc = bufA;
    float4*       bn = bufB;

#define LEVEL_BODY(LEV, GV)                                                     \
    gstep<LEV, 0>(a0, bc, bn, tid, F0, GV);                                     \
    gstep<LEV, 1>(a1, bc, bn, tid, F0, GV);                                     \
    gstep<LEV, 2>(a2, bc, bn, tid, F0, GV);                                     \
    gstep<LEV, 3>(a3, bc, bn, tid, F0, GV);                                     \
    gstep<LEV, 4>(a4, bc, bn, tid, F0, GV);                                     \
    gstep<LEV, 5>(a5, bc, bn, tid, F0, GV);                                     \
    gstep<LEV, 6>(a6, bc, bn, tid, F0, GV);                                     \
    gstep<LEV, 7>(a7, bc, bn, tid, F0, GV);

    // Levels 0..10: G1 = wi*F1; barrier + buffer swap after each.
#define DO_LEVEL(LEV)                                                           \
    {                                                                           \
        const float wi = wrow[MR_DEPTH - (LEV)];                                \
        const float4 G1 = make_float4(wi * F1.x, wi * F1.y, wi * F1.z, wi * F1.w); \
        LEVEL_BODY(LEV, G1)                                                     \
        __syncthreads();                                                        \
        const float4* t_ = bc; bc = bn; bn = (float4*)t_;                       \
    }

    DO_LEVEL(0)  DO_LEVEL(1)  DO_LEVEL(2)  DO_LEVEL(3)
    DO_LEVEL(4)  DO_LEVEL(5)  DO_LEVEL(6)  DO_LEVEL(7)
    DO_LEVEL(8)  DO_LEVEL(9)  DO_LEVEL(10)
#undef DO_LEVEL

    // Level 11 (last): fold w0*F0 into the accumulation coefficient.
    // acc += (w1*F1 + w0*F0) . taps  ==  w1*res_hi + w0*res_lo_final.
    // No nl computation, no LDS write, no barrier needed before epilogue
    // (epilogue writes bn, which level 11 never reads; level-10 reads of bn
    // were fenced by the barrier after level 10).
    {
        const float w1 = wrow[1];
        const float4 GX = make_float4(w1 * F1.x + w0 * F0.x,
                                      w1 * F1.y + w0 * F0.y,
                                      w1 * F1.z + w0 * F0.z,
                                      w1 * F1.w + w0 * F0.w);
        LEVEL_BODY(11, GX)
    }
#undef LEVEL_BODY

    // epilogue: exact-erf GELU on named accs -> transposed LDS -> coalesced store
    const float inv_sqrt2 = 0.70710678118654752f;
#define EPI(K, A) {                                                             \
        float4 vv; float u;                                                     \
        u = A.x; vv.x = 0.5f * u * (1.0f + erff(u * inv_sqrt2));                \
        u = A.y; vv.y = 0.5f * u * (1.0f + erff(u * inv_sqrt2));                \
        u = A.z; vv.z = 0.5f * u * (1.0f + erff(u * inv_sqrt2));                \
        u = A.w; vv.w = 0.5f * u * (1.0f + erff(u * inv_sqrt2));                \
        bn[((K) << 8) + tid] = vv; }
    EPI(0, a0) EPI(1, a1) EPI(2, a2) EPI(3, a3)
    EPI(4, a4) EPI(5, a5) EPI(6, a6) EPI(7, a7)
#undef EPI
    __syncthreads();

    float4* __restrict__ orow = (float4*)(out + (size_t)row * MR_L);
#pragma unroll
    for (int k = 0; k < 8; ++k)
        orow[tid + (k << 8)] = bn[sbase + k * 32];
}

extern "C" void kernel_launch(void* const* d_in, const int* in_sizes, int n_in,
                              void* d_out, int out_size, void* d_ws, size_t ws_size,
                              hipStream_t stream) {
    const float* x  = (const float*)d_in[0];
    const float* h0 = (const float*)d_in[1];
    const float* h1 = (const float*)d_in[2];
    const float* w  = (const float*)d_in[3];
    float* o        = (float*)d_out;

    const int rows = in_sizes[0] / MR_L;   // B*C = 4096
    multires_fused<<<rows, TPB, 0, stream>>>(x, h0, h1, w, o);
}

// Round 7
// 3841.703 us; speedup vs baseline: 1.3931x; 1.0278x over previous
//
#include <hip/hip_runtime.h>
#include <math.h>

#define MR_C     256
#define MR_L     8192
#define MR_DEPTH 12
#define TPB      256
#define NG       (MR_L / 4)    // 2048 float4 groups per row

// R8 THEORY: R6 proved the last failure mode — the level body (32 hoisted
// ds_read_b128 landing pads = 128 regs + 8 acc + temps ~ 270 demand) sits just
// above the heuristic 256-VGPR budget (2 waves/EU target), so the allocator
// spills ~20 regs -> 6.9 GB scratch round-trip at 1.8 TB/s = the runtime.
// TPB=256 kernels DO respect occupancy attributes (R5/R6 contrast), so force
// waves_per_eu(1,1): budget 512 vs ~270 demand -> zero spill. Occupancy drops
// to 4 waves/CU on paper, but measured occupancy was already ~3.7 waves/CU
// (spill-latency-crushed) — we lose nothing and remove all scratch traffic.
// Everything else identical to R6 (passed, absmax 0.0078).

__device__ __forceinline__ float4 f4z() { return make_float4(0.f, 0.f, 0.f, 0.f); }

// Read the tap at own-run-relative group index E (own group K, tap K-D).
// Own groups of thread t are g = t*8+k at LDS slot (k<<8)+t.
template<int E>
__device__ __forceinline__ float4 lds_tap(const float4* __restrict__ bc, const int tid)
{
    if constexpr (E >= 0) {
        return bc[(E << 8) + tid];
    } else {
        constexpr int em = ((E % 8) + 8) % 8;   // true mod 8
        constexpr int ef = (E - em) / 8;        // floor div 8 (negative)
        return (tid + ef >= 0) ? bc[(em << 8) + tid + ef] : f4z();   // causal zero-pad
    }
}

// One group-step. acc is ONE named float4 passed by reference (SROA-trivial).
// coefficient of x[t-d*j] is h[3-j]:  F.w*x[t] + F.z*x[t-d] + F.y*x[t-2d] + F.x*x[t-3d]
// G1 = wi*F1 pre-folded (and for LEV==11, G1 = w1*F1 + w0*F0: the final
// res_lo contribution merges into the last level -> no nl, no LDS write).
template<int LEV, int K>
__device__ __forceinline__ void gstep(
    float4& acc, const float4* __restrict__ bc, float4* __restrict__ bn,
    const int tid, const float4 F0, const float4 G1)
{
    constexpr int d = 1 << LEV;
    const float4 rl = bc[(K << 8) + tid];
    float4 t1, t2, t3;   // taps at t-d, t-2d, t-3d

    if constexpr (d == 1) {
        const float4 p = lds_tap<K - 1>(bc, tid);
        t1 = make_float4(p.w, rl.x, rl.y, rl.z);
        t2 = make_float4(p.z, p.w, rl.x, rl.y);
        t3 = make_float4(p.y, p.z, p.w, rl.x);
    } else if constexpr (d == 2) {
        const float4 p  = lds_tap<K - 1>(bc, tid);
        const float4 p2 = lds_tap<K - 2>(bc, tid);
        t1 = make_float4(p.z, p.w, rl.x, rl.y);
        t2 = p;
        t3 = make_float4(p2.z, p2.w, p.x, p.y);
    } else {
        constexpr int D4 = d >> 2;              // dilation in whole groups
        t1 = lds_tap<K -     D4>(bc, tid);
        t2 = lds_tap<K - 2 * D4>(bc, tid);
        t3 = lds_tap<K - 3 * D4>(bc, tid);
    }

    acc.x += G1.w * rl.x + G1.z * t1.x + G1.y * t2.x + G1.x * t3.x;
    acc.y += G1.w * rl.y + G1.z * t1.y + G1.y * t2.y + G1.x * t3.y;
    acc.z += G1.w * rl.z + G1.z * t1.z + G1.y * t2.z + G1.x * t3.z;
    acc.w += G1.w * rl.w + G1.z * t1.w + G1.y * t2.w + G1.x * t3.w;

    if constexpr (LEV != MR_DEPTH - 1) {
        float4 nl;
        nl.x = F0.w * rl.x + F0.z * t1.x + F0.y * t2.x + F0.x * t3.x;
        nl.y = F0.w * rl.y + F0.z * t1.y + F0.y * t2.y + F0.x * t3.y;
        nl.z = F0.w * rl.z + F0.z * t1.z + F0.y * t2.z + F0.x * t3.z;
        nl.w = F0.w * rl.w + F0.z * t1.w + F0.y * t2.w + F0.x * t3.w;
        bn[(K << 8) + tid] = nl;   // consecutive slots across lanes: conflict-free
    }
}

__global__ __launch_bounds__(TPB) __attribute__((amdgpu_waves_per_eu(1, 1)))
void multires_fused(
    const float* __restrict__ x,
    const float* __restrict__ h0,
    const float* __restrict__ h1,
    const float* __restrict__ w,
    float* __restrict__ out)
{
    __shared__ float4 bufA[NG];
    __shared__ float4 bufB[NG];   // 64 KiB total

    const int row = blockIdx.x;            // b*C + c
    const int c   = row & (MR_C - 1);
    const int tid = threadIdx.x;

    // block-uniform filter/weight loads -> scalar regs
    const float4 F0 = ((const float4*)h0)[c];
    const float4 F1 = ((const float4*)h1)[c];
    const float* __restrict__ wrow = w + c * (MR_DEPTH + 2);
    const float wlast = wrow[MR_DEPTH + 1];
    const float w0    = wrow[0];

    const float4* __restrict__ xrow = (const float4*)(x + (size_t)row * MR_L);

    // slot base for the strided (coalesced-global) <-> transposed-LDS bounce
    const int sbase = ((tid & 7) << 8) + (tid >> 3);

    // prologue: coalesced global loads, scatter into transposed LDS layout
#pragma unroll
    for (int k = 0; k < 8; ++k)
        bufA[sbase + k * 32] = xrow[tid + (k << 8)];
    __syncthreads();

    // init 8 NAMED accumulators: a_k = wlast * x(own group k)   (conflict-free reads)
    float4 a0, a1, a2, a3, a4, a5, a6, a7;
#define ACC_INIT(K, A) { const float4 t = bufA[((K) << 8) + tid];               \
        A = make_float4(wlast * t.x, wlast * t.y, wlast * t.z, wlast * t.w); }
    ACC_INIT(0, a0) ACC_INIT(1, a1) ACC_INIT(2, a2) ACC_INIT(3, a3)
    ACC_INIT(4, a4) ACC_INIT(5, a5) ACC_INIT(6, a6) ACC_INIT(7, a7)
#undef ACC_INIT

    const float4* bc = bufA;
    float4*       bn = bufB;

#define LEVEL_BODY(LEV, GV)                                                     \
    gstep<LEV, 0>(a0, bc, bn, tid, F0, GV);                                     \
    gstep<LEV, 1>(a1, bc, bn, tid, F0, GV);                                     \
    gstep<LEV, 2>(a2, bc, bn, tid, F0, GV);                                     \
    gstep<LEV, 3>(a3, bc, bn, tid, F0, GV);                                     \
    gstep<LEV, 4>(a4, bc, bn, tid, F0, GV);                                     \
    gstep<LEV, 5>(a5, bc, bn, tid, F0, GV);                                     \
    gstep<LEV, 6>(a6, bc, bn, tid, F0, GV);                                     \
    gstep<LEV, 7>(a7, bc, bn, tid, F0, GV);

    // Levels 0..10: G1 = wi*F1; barrier + buffer swap after each.
#define DO_LEVEL(LEV)                                                           \
    {                                                                           \
        const float wi = wrow[MR_DEPTH - (LEV)];                                \
        const float4 G1 = make_float4(wi * F1.x, wi * F1.y, wi * F1.z, wi * F1.w); \
        LEVEL_BODY(LEV, G1)                                                     \
        __syncthreads();                                                        \
        const float4* t_ = bc; bc = bn; bn = (float4*)t_;                       \
    }

    DO_LEVEL(0)  DO_LEVEL(1)  DO_LEVEL(2)  DO_LEVEL(3)
    DO_LEVEL(4)  DO_LEVEL(5)  DO_LEVEL(6)  DO_LEVEL(7)
    DO_LEVEL(8)  DO_LEVEL(9)  DO_LEVEL(10)
#undef DO_LEVEL

    // Level 11 (last): fold w0*F0 into the accumulation coefficient.
    // acc += (w1*F1 + w0*F0) . taps  ==  w1*res_hi + w0*res_lo_final.
    // No nl computation, no LDS write, no barrier needed before epilogue
    // (epilogue writes bn, which level 11 never reads; level-10 reads of bn
    // were fenced by the barrier after level 10).
    {
        const float w1 = wrow[1];
        const float4 GX = make_float4(w1 * F1.x + w0 * F0.x,
                                      w1 * F1.y + w0 * F0.y,
                                      w1 * F1.z + w0 * F0.z,
                                      w1 * F1.w + w0 * F0.w);
        LEVEL_BODY(11, GX)
    }
#undef LEVEL_BODY

    // epilogue: exact-erf GELU on named accs -> transposed LDS -> coalesced store
    const float inv_sqrt2 = 0.70710678118654752f;
#define EPI(K, A) {                                                             \
        float4 vv; float u;                                                     \
        u = A.x; vv.x = 0.5f * u * (1.0f + erff(u * inv_sqrt2));                \
        u = A.y; vv.y = 0.5f * u * (1.0f + erff(u * inv_sqrt2));                \
        u = A.z; vv.z = 0.5f * u * (1.0f + erff(u * inv_sqrt2));                \
        u = A.w; vv.w = 0.5f * u * (1.0f + erff(u * inv_sqrt2));                \
        bn[((K) << 8) + tid] = vv; }
    EPI(0, a0) EPI(1, a1) EPI(2, a2) EPI(3, a3)
    EPI(4, a4) EPI(5, a5) EPI(6, a6) EPI(7, a7)
#undef EPI
    __syncthreads();

    float4* __restrict__ orow = (float4*)(out + (size_t)row * MR_L);
#pragma unroll
    for (int k = 0; k < 8; ++k)
        orow[tid + (k << 8)] = bn[sbase + k * 32];
}

extern "C" void kernel_launch(void* const* d_in, const int* in_sizes, int n_in,
                              void* d_out, int out_size, void* d_ws, size_t ws_size,
                              hipStream_t stream) {
    const float* x  = (const float*)d_in[0];
    const float* h0 = (const float*)d_in[1];
    const float* h1 = (const float*)d_in[2];
    const float* w  = (const float*)d_in[3];
    float* o        = (float*)d_out;

    const int rows = in_sizes[0] / MR_L;   // B*C = 4096
    multires_fused<<<rows, TPB, 0, stream>>>(x, h0, h1, w, o);
}